// Round 18
// baseline (710.850 us; speedup 1.0000x reference)
//
#include <hip/hip_runtime.h>

#define TT 512
#define NB 128   // batch
#define DD 128
#define HH 64
#define CC 45

__device__ __forceinline__ float sigf(float x) { return 1.0f / (1.0f + __expf(-x)); }

// LDS-only barrier: syncs LDS visibility WITHOUT draining vmcnt.
#define LDS_BAR() asm volatile("s_waitcnt lgkmcnt(0)\n\ts_barrier" ::: "memory")

// Quad-lane xor via DPP quad_perm (VALU ~2cy; semantics proven R9/R12).
#define QP_XOR1(x) __int_as_float(__builtin_amdgcn_mov_dpp(__float_as_int(x), 0xB1, 0xF, 0xF, true))
#define QP_XOR2(x) __int_as_float(__builtin_amdgcn_mov_dpp(__float_as_int(x), 0x4E, 0xF, 0xF, true))

// bf16 helpers (RN rounding), ushort carries the bit pattern.
__device__ __forceinline__ ushort f2bf(float x) {
    uint u = __float_as_uint(x);
    u += 0x7FFFu + ((u >> 16) & 1u);
    return (ushort)(u >> 16);
}
__device__ __forceinline__ float bf2f(ushort h) { return __uint_as_float(((uint)h) << 16); }

typedef short short8 __attribute__((ext_vector_type(8)));
typedef float f32x4 __attribute__((ext_vector_type(4)));

// ---------------------------------------------------------------------------
// GEMM v2 via split-bf16 MFMA (R15, proven ~45us/dispatch).
// ---------------------------------------------------------------------------
__global__ __launch_bounds__(256, 2) void gemm_xz_mfma2(
    const float* __restrict__ A, const float* __restrict__ Wf,
    const float* __restrict__ Wb, const float* __restrict__ biasf,
    const float* __restrict__ biasb, float* __restrict__ Cout)
{
    __shared__ ushort Wh[128][136];
    __shared__ ushort Wl[128][136];

    const int tid = threadIdx.x;
    const int n0  = blockIdx.x * 128;
    const int m0  = blockIdx.y * 128;
    const float* W   = (n0 < 256) ? Wf : Wb;
    const float* bia = (n0 < 256) ? biasf : biasb;
    const int nc0 = n0 & 255;

    {
        const int r  = tid >> 1;
        const int cb = (tid & 1) * 64;
        #pragma unroll
        for (int i = 0; i < 16; ++i) {
            const int c = cb + i * 4;
            const float4 wv = *(const float4*)&W[(size_t)r * 256 + nc0 + c];
            const ushort h0 = (ushort)(__float_as_uint(wv.x) >> 16);
            const ushort h1 = (ushort)(__float_as_uint(wv.y) >> 16);
            const ushort h2 = (ushort)(__float_as_uint(wv.z) >> 16);
            const ushort h3 = (ushort)(__float_as_uint(wv.w) >> 16);
            Wh[c + 0][r] = h0; Wl[c + 0][r] = f2bf(wv.x - bf2f(h0));
            Wh[c + 1][r] = h1; Wl[c + 1][r] = f2bf(wv.y - bf2f(h1));
            Wh[c + 2][r] = h2; Wl[c + 2][r] = f2bf(wv.z - bf2f(h2));
            Wh[c + 3][r] = h3; Wl[c + 3][r] = f2bf(wv.w - bf2f(h3));
        }
    }
    __syncthreads();

    const int lane = tid & 63, wv_ = tid >> 6;
    const int fr = lane & 15, fg = lane >> 4;

    f32x4 acc[2][8];
    #pragma unroll
    for (int ms = 0; ms < 2; ++ms)
        #pragma unroll
        for (int nt = 0; nt < 8; ++nt) acc[ms][nt] = (f32x4){0.f, 0.f, 0.f, 0.f};

    #pragma unroll
    for (int ks = 0; ks < 4; ++ks) {
        const int kb = ks * 32 + fg * 8;
        short8 ah[2], al[2];
        #pragma unroll
        for (int ms = 0; ms < 2; ++ms) {
            const float* ap = &A[(size_t)(m0 + wv_ * 32 + ms * 16 + fr) * 128 + kb];
            const float4 va = *(const float4*)ap;
            const float4 vb = *(const float4*)(ap + 4);
            float v[8] = {va.x, va.y, va.z, va.w, vb.x, vb.y, vb.z, vb.w};
            #pragma unroll
            for (int j = 0; j < 8; ++j) {
                const ushort hj = (ushort)(__float_as_uint(v[j]) >> 16);
                ah[ms][j] = (short)hj;
                al[ms][j] = (short)f2bf(v[j] - bf2f(hj));
            }
        }
        #pragma unroll
        for (int nt = 0; nt < 8; ++nt) {
            const short8 bh = *(const short8*)&Wh[nt * 16 + fr][kb];
            const short8 bl = *(const short8*)&Wl[nt * 16 + fr][kb];
            acc[0][nt] = __builtin_amdgcn_mfma_f32_16x16x32_bf16(ah[0], bh, acc[0][nt], 0, 0, 0);
            acc[0][nt] = __builtin_amdgcn_mfma_f32_16x16x32_bf16(ah[0], bl, acc[0][nt], 0, 0, 0);
            acc[0][nt] = __builtin_amdgcn_mfma_f32_16x16x32_bf16(al[0], bh, acc[0][nt], 0, 0, 0);
            acc[1][nt] = __builtin_amdgcn_mfma_f32_16x16x32_bf16(ah[1], bh, acc[1][nt], 0, 0, 0);
            acc[1][nt] = __builtin_amdgcn_mfma_f32_16x16x32_bf16(ah[1], bl, acc[1][nt], 0, 0, 0);
            acc[1][nt] = __builtin_amdgcn_mfma_f32_16x16x32_bf16(al[1], bh, acc[1][nt], 0, 0, 0);
        }
    }

    #pragma unroll
    for (int nt = 0; nt < 8; ++nt) {
        const float bb = bia[nc0 + nt * 16 + fr];
        #pragma unroll
        for (int ms = 0; ms < 2; ++ms) {
            #pragma unroll
            for (int j = 0; j < 4; ++j) {
                const int mg = m0 + wv_ * 32 + ms * 16 + fg * 4 + j;
                Cout[(size_t)mg * 512 + n0 + nt * 16 + fr] = acc[ms][nt][j] + bb;
            }
        }
    }
}

// ---------------------------------------------------------------------------
// LSTM recurrence — HYBRID U: 16 values/lane from LDS + 16 from L2.
// Rationale (R12-R17 forensics): streaming all 32 U from L2 = 16MB/step
// chip-wide = L2 roofline 238us (R12 measures 245, 99%). Resident-register
// U impossible (RA remat/spill, 10 rounds) and issue-bound anyway (R14/R17).
// The DS pipe (~85-128B/cyc/CU) is IDLE-ish in R12 — so route half of U
// through it: DS(U 4xb128 + h bcast) ~770cyc || L2(32KB/56B/cyc) ~585cyc
// => ~770-900 cyc/step vs 1150.
// Structure = R12 (proven): 256 blocks x 512thr, lane [1:0]=gate [4:2]=colL
// [5]=kh; K-half reduce shfl_xor(32); gate gather 3 QP DPP; one LDS_BAR.
// U-LDS layout: row r=col*4+gate, stride 44 floats (11x16B, odd) => each
// consecutive lane-octet hits all 8 distinct 16B bank-columns (derived;
// falsifiable via SQ_LDS_BANK_CONFLICT).
// ---------------------------------------------------------------------------
__global__
__attribute__((amdgpu_flat_work_group_size(512, 512), amdgpu_waves_per_eu(1, 2)))
void lstm_rec_hy(
    const float* __restrict__ xz, const float* __restrict__ Uf,
    const float* __restrict__ Ubw, float* __restrict__ hout)
{
    const int b   = blockIdx.x & 127;
    const int dir = blockIdx.x >> 7;
    const int tid = threadIdx.x;
    const int w    = tid >> 6;          // wave 0..7
    const int lane = tid & 63;
    const int gate = lane & 3;          // 0:i 1:f 2:g 3:o (quad -> DPP gather)
    const int colL = (lane >> 2) & 7;
    const int kh   = lane >> 5;         // K-half 0/1
    const int col  = w * 8 + colL;      // h column 0..63
    const int gcol = gate * 64 + col;
    const float* U = dir ? Ubw : Uf;

    __shared__ float hbuf[2][64];
    __shared__ float Ulds[256][44];     // row r=col*4+gate; [kh*16+j] used

    // ---- stage first 16 k of each K-half into LDS (8192 floats, once) ----
    for (int idx = tid; idx < 8192; idx += 512) {
        const int j  = idx & 15;
        const int k2 = (idx >> 4) & 1;          // kh
        const int r  = idx >> 5;                // 0..255
        const int gg = r & 3, cc = r >> 2;
        Ulds[r][k2 * 16 + j] = U[(size_t)(k2 * 32 + j) * 256 + gg * 64 + cc];
    }

    if (tid < 64) hbuf[0][tid] = 0.f;
    float c = 0.f;
    __syncthreads();

    // L2-streamed quarter: k = kh*32 + 16 + j, j=0..15 (R12-proven pattern)
    const float* Ug2 = U + (size_t)(kh * 32 + 16) * 256 + gcol;
    const float* Ul  = &Ulds[col * 4 + gate][kh * 16];

    const float* xzb = xz + (size_t)b * TT * 512 + (size_t)dir * 256 + gcol;
    float*       hob = hout + (size_t)b * TT * 128 + (size_t)dir * 64 + col;

    int trow = dir ? (TT - 1) : 0;
    const int ts = dir ? -1 : 1;
    float xc = xzb[(size_t)trow * 512];            // step s
    float x1 = xzb[(size_t)(trow + ts) * 512];     // step s+1

    for (int s = 0; s < TT; ++s) {
        const int p = s & 1;
        float x2 = 0.f;
        if (s + 2 < TT) x2 = xzb[(size_t)(trow + 2 * ts) * 512];  // depth-2

        float a0 = 0.f, a1 = 0.f, a2 = 0.f, a3 = 0.f;

        // ---- LDS quarter: k = kh*32 + 0..15 (4 b128 U reads + 4 h bcast) ----
        {
            const float4 uA = *(const float4*)&Ul[0];
            const float4 uB = *(const float4*)&Ul[4];
            const float4 uC = *(const float4*)&Ul[8];
            const float4 uD = *(const float4*)&Ul[12];
            const float4 hA = *(const float4*)&hbuf[p][kh * 32 + 0];
            const float4 hB = *(const float4*)&hbuf[p][kh * 32 + 4];
            const float4 hC = *(const float4*)&hbuf[p][kh * 32 + 8];
            const float4 hD = *(const float4*)&hbuf[p][kh * 32 + 12];
            a0 = __fmaf_rn(hA.x, uA.x, a0); a1 = __fmaf_rn(hA.y, uA.y, a1);
            a2 = __fmaf_rn(hA.z, uA.z, a2); a3 = __fmaf_rn(hA.w, uA.w, a3);
            a0 = __fmaf_rn(hB.x, uB.x, a0); a1 = __fmaf_rn(hB.y, uB.y, a1);
            a2 = __fmaf_rn(hB.z, uB.z, a2); a3 = __fmaf_rn(hB.w, uB.w, a3);
            a0 = __fmaf_rn(hC.x, uC.x, a0); a1 = __fmaf_rn(hC.y, uC.y, a1);
            a2 = __fmaf_rn(hC.z, uC.z, a2); a3 = __fmaf_rn(hC.w, uC.w, a3);
            a0 = __fmaf_rn(hD.x, uD.x, a0); a1 = __fmaf_rn(hD.y, uD.y, a1);
            a2 = __fmaf_rn(hD.z, uD.z, a2); a3 = __fmaf_rn(hD.w, uD.w, a3);
        }
        // ---- L2 quarter: k = kh*32 + 16..31 (16 in-loop global loads) ----
        {
            const float4 hA = *(const float4*)&hbuf[p][kh * 32 + 16];
            const float4 hB = *(const float4*)&hbuf[p][kh * 32 + 20];
            const float4 hC = *(const float4*)&hbuf[p][kh * 32 + 24];
            const float4 hD = *(const float4*)&hbuf[p][kh * 32 + 28];
            a0 = __fmaf_rn(hA.x, Ug2[ 0 * 256], a0); a1 = __fmaf_rn(hA.y, Ug2[ 1 * 256], a1);
            a2 = __fmaf_rn(hA.z, Ug2[ 2 * 256], a2); a3 = __fmaf_rn(hA.w, Ug2[ 3 * 256], a3);
            a0 = __fmaf_rn(hB.x, Ug2[ 4 * 256], a0); a1 = __fmaf_rn(hB.y, Ug2[ 5 * 256], a1);
            a2 = __fmaf_rn(hB.z, Ug2[ 6 * 256], a2); a3 = __fmaf_rn(hB.w, Ug2[ 7 * 256], a3);
            a0 = __fmaf_rn(hC.x, Ug2[ 8 * 256], a0); a1 = __fmaf_rn(hC.y, Ug2[ 9 * 256], a1);
            a2 = __fmaf_rn(hC.z, Ug2[10 * 256], a2); a3 = __fmaf_rn(hC.w, Ug2[11 * 256], a3);
            a0 = __fmaf_rn(hD.x, Ug2[12 * 256], a0); a1 = __fmaf_rn(hD.y, Ug2[13 * 256], a1);
            a2 = __fmaf_rn(hD.z, Ug2[14 * 256], a2); a3 = __fmaf_rn(hD.w, Ug2[15 * 256], a3);
        }
        float part = (a0 + a1) + (a2 + a3);

        part += __shfl_xor(part, 32);   // K-half reduce (proven)
        const float z = xc + part;

        const float a = (gate == 2) ? fmaxf(z, 0.f) : sigf(z);

        const float b0 = QP_XOR1(a);
        const float b1 = QP_XOR2(a);
        const float b2 = QP_XOR2(b0);
        const float ai = (gate == 0) ? a : (gate == 1) ? b0 : (gate == 2) ? b1 : b2;
        const float af = (gate == 1) ? a : (gate == 0) ? b0 : (gate == 3) ? b1 : b2;
        const float ag = (gate == 2) ? a : (gate == 3) ? b0 : (gate == 0) ? b1 : b2;
        const float ao = (gate == 3) ? a : (gate == 2) ? b0 : (gate == 1) ? b1 : b2;

        c = af * c + ai * ag;
        const float h = ao * fmaxf(c, 0.f);

        if ((lane & 0x23) == 0) {           // writer: gate==0 && kh==0
            hbuf[p ^ 1][col] = h;
            hob[(size_t)trow * 128] = h;    // fire-and-forget, never drained
        }

        LDS_BAR();                          // ONE barrier/step; WAR safe (parity)

        xc = x1; x1 = x2;
        trow += ts;
    }
}

// ---------------------------------------------------------------------------
// Dense + softmax: out[m][c] = softmax_c( h2[m][:] @ Wd[:,c] + bd[c] )
// ---------------------------------------------------------------------------
__global__ __launch_bounds__(256) void dense_softmax(
    const float* __restrict__ h2, const float* __restrict__ Wd,
    const float* __restrict__ bd, float* __restrict__ out)
{
    __shared__ float Wl[128 * 45];
    __shared__ float bl[48];
    __shared__ float hrow[4][128];
    const int tid = threadIdx.x;
    for (int i = tid; i < 128 * 45; i += 256) Wl[i] = Wd[i];
    if (tid < 45) bl[tid] = bd[tid];
    __syncthreads();

    const int w = tid >> 6, l = tid & 63;
    const size_t row0 = (size_t)blockIdx.x * 64;
    for (int rr = 0; rr < 16; ++rr) {
        const size_t m = row0 + (size_t)rr * 4 + w;
        const float2 hv = *(const float2*)&h2[m * 128 + l * 2];
        hrow[w][l * 2] = hv.x;
        hrow[w][l * 2 + 1] = hv.y;
        __syncthreads();
        float lg = -3.0e38f;
        if (l < CC) {
            lg = bl[l];
            #pragma unroll 8
            for (int k = 0; k < 128; ++k) lg = __fmaf_rn(hrow[w][k], Wl[k * 45 + l], lg);
        }
        float mx = lg;
        #pragma unroll
        for (int off = 32; off >= 1; off >>= 1) mx = fmaxf(mx, __shfl_xor(mx, off));
        const float e = (l < CC) ? __expf(lg - mx) : 0.f;
        float sm = e;
        #pragma unroll
        for (int off = 32; off >= 1; off >>= 1) sm += __shfl_xor(sm, off);
        if (l < CC) out[m * 45 + l] = e / sm;
        __syncthreads();
    }
}

// ---------------------------------------------------------------------------
extern "C" void kernel_launch(void* const* d_in, const int* in_sizes, int n_in,
                              void* d_out, int out_size, void* d_ws, size_t ws_size,
                              hipStream_t stream)
{
    const float* x   = (const float*)d_in[0];
    const float* W1f = (const float*)d_in[1];
    const float* U1f = (const float*)d_in[2];
    const float* b1f = (const float*)d_in[3];
    const float* W1b = (const float*)d_in[4];
    const float* U1b = (const float*)d_in[5];
    const float* b1b = (const float*)d_in[6];
    const float* W2f = (const float*)d_in[7];
    const float* U2f = (const float*)d_in[8];
    const float* b2f = (const float*)d_in[9];
    const float* W2b = (const float*)d_in[10];
    const float* U2b = (const float*)d_in[11];
    const float* b2b = (const float*)d_in[12];
    const float* Wd  = (const float*)d_in[13];
    const float* bd  = (const float*)d_in[14];

    // Workspace layout (160 MiB):
    //   xz : 65536 x 512 f32 = 128 MiB   (reused by layer 1 and layer 2)
    //   h  : 65536 x 128 f32 =  32 MiB   (h1, then overwritten by h2)
    float* xz = (float*)d_ws;
    float* h  = (float*)((char*)d_ws + (size_t)65536 * 512 * 4);

    const dim3 gemm_grid(4, 512);      // n-tile FASTEST (A-tile L2 sharing)
    const dim3 rec_grid(256);          // 128 batch x 2 directions
    const dim3 dense_grid(1024);       // 65536/64 rows

    // Layer 1
    gemm_xz_mfma2<<<gemm_grid, dim3(256), 0, stream>>>(x, W1f, W1b, b1f, b1b, xz);
    lstm_rec_hy<<<rec_grid, dim3(512), 0, stream>>>(xz, U1f, U1b, h);
    // Layer 2
    gemm_xz_mfma2<<<gemm_grid, dim3(256), 0, stream>>>(h, W2f, W2b, b2f, b2b, xz);
    lstm_rec_hy<<<rec_grid, dim3(512), 0, stream>>>(xz, U2f, U2b, h);
    // Head
    dense_softmax<<<dense_grid, dim3(256), 0, stream>>>(h, Wd, bd, (float*)d_out);
}

// Round 20
// 604.161 us; speedup vs baseline: 1.1766x; 1.1766x over previous
//
#include <hip/hip_runtime.h>

#define TT 512
#define NB 128   // batch
#define DD 128
#define HH 64
#define CC 45

__device__ __forceinline__ float sigf(float x) { return 1.0f / (1.0f + __expf(-x)); }

// LDS-only barrier: syncs LDS visibility WITHOUT draining vmcnt.
#define LDS_BAR() asm volatile("s_waitcnt lgkmcnt(0)\n\ts_barrier" ::: "memory")

// Quad-lane xor via DPP quad_perm (VALU ~2cy; semantics proven R9/R12).
#define QP_XOR1(x) __int_as_float(__builtin_amdgcn_mov_dpp(__float_as_int(x), 0xB1, 0xF, 0xF, true))
#define QP_XOR2(x) __int_as_float(__builtin_amdgcn_mov_dpp(__float_as_int(x), 0x4E, 0xF, 0xF, true))

// bf16 helpers (RN rounding), ushort carries the bit pattern.
__device__ __forceinline__ ushort f2bf(float x) {
    uint u = __float_as_uint(x);
    u += 0x7FFFu + ((u >> 16) & 1u);
    return (ushort)(u >> 16);
}
__device__ __forceinline__ float bf2f(ushort h) { return __uint_as_float(((uint)h) << 16); }

typedef short short8 __attribute__((ext_vector_type(8)));
typedef float f32x4 __attribute__((ext_vector_type(4)));

// ---------------------------------------------------------------------------
// GEMM v2 via split-bf16 MFMA (R15, proven ~45us/dispatch).
// A-fragments loaded directly from global (L2-hot) and trunc-split in
// registers; W staged in LDS (transposed [n][k]); 68KB LDS => 2 blocks/CU.
// ---------------------------------------------------------------------------
__global__ __launch_bounds__(256, 2) void gemm_xz_mfma2(
    const float* __restrict__ A, const float* __restrict__ Wf,
    const float* __restrict__ Wb, const float* __restrict__ biasf,
    const float* __restrict__ biasb, float* __restrict__ Cout)
{
    __shared__ ushort Wh[128][136];
    __shared__ ushort Wl[128][136];

    const int tid = threadIdx.x;
    const int n0  = blockIdx.x * 128;
    const int m0  = blockIdx.y * 128;
    const float* W   = (n0 < 256) ? Wf : Wb;
    const float* bia = (n0 < 256) ? biasf : biasb;
    const int nc0 = n0 & 255;

    {
        const int r  = tid >> 1;
        const int cb = (tid & 1) * 64;
        #pragma unroll
        for (int i = 0; i < 16; ++i) {
            const int c = cb + i * 4;
            const float4 wv = *(const float4*)&W[(size_t)r * 256 + nc0 + c];
            const ushort h0 = (ushort)(__float_as_uint(wv.x) >> 16);
            const ushort h1 = (ushort)(__float_as_uint(wv.y) >> 16);
            const ushort h2 = (ushort)(__float_as_uint(wv.z) >> 16);
            const ushort h3 = (ushort)(__float_as_uint(wv.w) >> 16);
            Wh[c + 0][r] = h0; Wl[c + 0][r] = f2bf(wv.x - bf2f(h0));
            Wh[c + 1][r] = h1; Wl[c + 1][r] = f2bf(wv.y - bf2f(h1));
            Wh[c + 2][r] = h2; Wl[c + 2][r] = f2bf(wv.z - bf2f(h2));
            Wh[c + 3][r] = h3; Wl[c + 3][r] = f2bf(wv.w - bf2f(h3));
        }
    }
    __syncthreads();

    const int lane = tid & 63, wv_ = tid >> 6;
    const int fr = lane & 15, fg = lane >> 4;

    f32x4 acc[2][8];
    #pragma unroll
    for (int ms = 0; ms < 2; ++ms)
        #pragma unroll
        for (int nt = 0; nt < 8; ++nt) acc[ms][nt] = (f32x4){0.f, 0.f, 0.f, 0.f};

    #pragma unroll
    for (int ks = 0; ks < 4; ++ks) {
        const int kb = ks * 32 + fg * 8;
        short8 ah[2], al[2];
        #pragma unroll
        for (int ms = 0; ms < 2; ++ms) {
            const float* ap = &A[(size_t)(m0 + wv_ * 32 + ms * 16 + fr) * 128 + kb];
            const float4 va = *(const float4*)ap;
            const float4 vb = *(const float4*)(ap + 4);
            float v[8] = {va.x, va.y, va.z, va.w, vb.x, vb.y, vb.z, vb.w};
            #pragma unroll
            for (int j = 0; j < 8; ++j) {
                const ushort hj = (ushort)(__float_as_uint(v[j]) >> 16);
                ah[ms][j] = (short)hj;
                al[ms][j] = (short)f2bf(v[j] - bf2f(hj));
            }
        }
        #pragma unroll
        for (int nt = 0; nt < 8; ++nt) {
            const short8 bh = *(const short8*)&Wh[nt * 16 + fr][kb];
            const short8 bl = *(const short8*)&Wl[nt * 16 + fr][kb];
            acc[0][nt] = __builtin_amdgcn_mfma_f32_16x16x32_bf16(ah[0], bh, acc[0][nt], 0, 0, 0);
            acc[0][nt] = __builtin_amdgcn_mfma_f32_16x16x32_bf16(ah[0], bl, acc[0][nt], 0, 0, 0);
            acc[0][nt] = __builtin_amdgcn_mfma_f32_16x16x32_bf16(al[0], bh, acc[0][nt], 0, 0, 0);
            acc[1][nt] = __builtin_amdgcn_mfma_f32_16x16x32_bf16(ah[1], bh, acc[1][nt], 0, 0, 0);
            acc[1][nt] = __builtin_amdgcn_mfma_f32_16x16x32_bf16(ah[1], bl, acc[1][nt], 0, 0, 0);
            acc[1][nt] = __builtin_amdgcn_mfma_f32_16x16x32_bf16(al[1], bh, acc[1][nt], 0, 0, 0);
        }
    }

    #pragma unroll
    for (int nt = 0; nt < 8; ++nt) {
        const float bb = bia[nc0 + nt * 16 + fr];
        #pragma unroll
        for (int ms = 0; ms < 2; ++ms) {
            #pragma unroll
            for (int j = 0; j < 4; ++j) {
                const int mg = m0 + wv_ * 32 + ms * 16 + fg * 4 + j;
                Cout[(size_t)mg * 512 + n0 + nt * 16 + fr] = acc[ms][nt][j] + bb;
            }
        }
    }
}

// ---------------------------------------------------------------------------
// LSTM recurrence (R12 exact — empirical floor: 245.2us/dispatch, absmax
// 2.44e-4, verified best across 8 structural variants R8-R19).
// 256 blocks (batch x dir) x 512 threads. Lane bits: [1:0]=gate, [4:2]=colL,
// [5]=kh. Wave owns 8 cols; 32 in-loop U loads (L2-resident); 32 FMA;
// K-half reduce via __shfl_xor(32); gate gather via 3 DPP quad_perm;
// ONE LDS_BAR/step; depth-2 xz prefetch; fire-and-forget h stores.
// ---------------------------------------------------------------------------
__global__
__attribute__((amdgpu_flat_work_group_size(512, 512), amdgpu_waves_per_eu(1, 2)))
void lstm_rec_qp(
    const float* __restrict__ xz, const float* __restrict__ Uf,
    const float* __restrict__ Ubw, float* __restrict__ hout)
{
    const int b   = blockIdx.x & 127;
    const int dir = blockIdx.x >> 7;
    const int tid = threadIdx.x;
    const int w    = tid >> 6;          // wave 0..7
    const int lane = tid & 63;
    const int gate = lane & 3;          // 0:i 1:f 2:g 3:o (quad -> DPP gather)
    const int colL = (lane >> 2) & 7;
    const int kh   = lane >> 5;         // K-half 0/1
    const int col  = w * 8 + colL;      // h column 0..63
    const int gcol = gate * 64 + col;
    const float* U = dir ? Ubw : Uf;

    __shared__ float hbuf[2][64];

    const float* Ug = U + (size_t)(kh * 32) * 256 + gcol;
    float u0  = Ug[ 0*256], u1  = Ug[ 1*256], u2  = Ug[ 2*256], u3  = Ug[ 3*256];
    float u4  = Ug[ 4*256], u5  = Ug[ 5*256], u6  = Ug[ 6*256], u7  = Ug[ 7*256];
    float u8  = Ug[ 8*256], u9  = Ug[ 9*256], u10 = Ug[10*256], u11 = Ug[11*256];
    float u12 = Ug[12*256], u13 = Ug[13*256], u14 = Ug[14*256], u15 = Ug[15*256];
    float u16 = Ug[16*256], u17 = Ug[17*256], u18 = Ug[18*256], u19 = Ug[19*256];
    float u20 = Ug[20*256], u21 = Ug[21*256], u22 = Ug[22*256], u23 = Ug[23*256];
    float u24 = Ug[24*256], u25 = Ug[25*256], u26 = Ug[26*256], u27 = Ug[27*256];
    float u28 = Ug[28*256], u29 = Ug[29*256], u30 = Ug[30*256], u31 = Ug[31*256];
    asm volatile("" : "+v"(u0),"+v"(u1),"+v"(u2),"+v"(u3),
                      "+v"(u4),"+v"(u5),"+v"(u6),"+v"(u7));
    asm volatile("" : "+v"(u8),"+v"(u9),"+v"(u10),"+v"(u11),
                      "+v"(u12),"+v"(u13),"+v"(u14),"+v"(u15));
    asm volatile("" : "+v"(u16),"+v"(u17),"+v"(u18),"+v"(u19),
                      "+v"(u20),"+v"(u21),"+v"(u22),"+v"(u23));
    asm volatile("" : "+v"(u24),"+v"(u25),"+v"(u26),"+v"(u27),
                      "+v"(u28),"+v"(u29),"+v"(u30),"+v"(u31));

    if (tid < 64) hbuf[0][tid] = 0.f;
    float c = 0.f;
    __syncthreads();

    const float* xzb = xz + (size_t)b * TT * 512 + (size_t)dir * 256 + gcol;
    float*       hob = hout + (size_t)b * TT * 128 + (size_t)dir * 64 + col;

    int trow = dir ? (TT - 1) : 0;
    const int ts = dir ? -1 : 1;
    float xc = xzb[(size_t)trow * 512];            // step s
    float x1 = xzb[(size_t)(trow + ts) * 512];     // step s+1

    for (int s = 0; s < TT; ++s) {
        const int p = s & 1;
        float x2 = 0.f;
        if (s + 2 < TT) x2 = xzb[(size_t)(trow + 2 * ts) * 512];  // depth-2

        float a0 = 0.f, a1 = 0.f, a2 = 0.f, a3 = 0.f;
#define ACC(J, A,B,C,D) { const float4 hv = *(const float4*)&hbuf[p][kh*32 + 4*(J)]; \
        a0 = __fmaf_rn(hv.x, A, a0); a1 = __fmaf_rn(hv.y, B, a1); \
        a2 = __fmaf_rn(hv.z, C, a2); a3 = __fmaf_rn(hv.w, D, a3); }
        ACC(0,u0 ,u1 ,u2 ,u3 ) ACC(1,u4 ,u5 ,u6 ,u7 )
        ACC(2,u8 ,u9 ,u10,u11) ACC(3,u12,u13,u14,u15)
        ACC(4,u16,u17,u18,u19) ACC(5,u20,u21,u22,u23)
        ACC(6,u24,u25,u26,u27) ACC(7,u28,u29,u30,u31)
#undef ACC
        float part = (a0 + a1) + (a2 + a3);

        part += __shfl_xor(part, 32);   // K-half reduce (proven)
        const float z = xc + part;

        const float a = (gate == 2) ? fmaxf(z, 0.f) : sigf(z);

        const float b0 = QP_XOR1(a);
        const float b1 = QP_XOR2(a);
        const float b2 = QP_XOR2(b0);
        const float ai = (gate == 0) ? a : (gate == 1) ? b0 : (gate == 2) ? b1 : b2;
        const float af = (gate == 1) ? a : (gate == 0) ? b0 : (gate == 3) ? b1 : b2;
        const float ag = (gate == 2) ? a : (gate == 3) ? b0 : (gate == 0) ? b1 : b2;
        const float ao = (gate == 3) ? a : (gate == 2) ? b0 : (gate == 1) ? b1 : b2;

        c = af * c + ai * ag;
        const float h = ao * fmaxf(c, 0.f);

        if ((lane & 0x23) == 0) {           // writer: gate==0 && kh==0
            hbuf[p ^ 1][col] = h;
            hob[(size_t)trow * 128] = h;    // fire-and-forget, never drained
        }

        LDS_BAR();                          // ONE barrier/step; WAR safe (parity)

        xc = x1; x1 = x2;
        trow += ts;
    }
}

// ---------------------------------------------------------------------------
// Dense + softmax: out[m][c] = softmax_c( h2[m][:] @ Wd[:,c] + bd[c] )
// ---------------------------------------------------------------------------
__global__ __launch_bounds__(256) void dense_softmax(
    const float* __restrict__ h2, const float* __restrict__ Wd,
    const float* __restrict__ bd, float* __restrict__ out)
{
    __shared__ float Wl[128 * 45];
    __shared__ float bl[48];
    __shared__ float hrow[4][128];
    const int tid = threadIdx.x;
    for (int i = tid; i < 128 * 45; i += 256) Wl[i] = Wd[i];
    if (tid < 45) bl[tid] = bd[tid];
    __syncthreads();

    const int w = tid >> 6, l = tid & 63;
    const size_t row0 = (size_t)blockIdx.x * 64;
    for (int rr = 0; rr < 16; ++rr) {
        const size_t m = row0 + (size_t)rr * 4 + w;
        const float2 hv = *(const float2*)&h2[m * 128 + l * 2];
        hrow[w][l * 2] = hv.x;
        hrow[w][l * 2 + 1] = hv.y;
        __syncthreads();
        float lg = -3.0e38f;
        if (l < CC) {
            lg = bl[l];
            #pragma unroll 8
            for (int k = 0; k < 128; ++k) lg = __fmaf_rn(hrow[w][k], Wl[k * 45 + l], lg);
        }
        float mx = lg;
        #pragma unroll
        for (int off = 32; off >= 1; off >>= 1) mx = fmaxf(mx, __shfl_xor(mx, off));
        const float e = (l < CC) ? __expf(lg - mx) : 0.f;
        float sm = e;
        #pragma unroll
        for (int off = 32; off >= 1; off >>= 1) sm += __shfl_xor(sm, off);
        if (l < CC) out[m * 45 + l] = e / sm;
        __syncthreads();
    }
}

// ---------------------------------------------------------------------------
extern "C" void kernel_launch(void* const* d_in, const int* in_sizes, int n_in,
                              void* d_out, int out_size, void* d_ws, size_t ws_size,
                              hipStream_t stream)
{
    const float* x   = (const float*)d_in[0];
    const float* W1f = (const float*)d_in[1];
    const float* U1f = (const float*)d_in[2];
    const float* b1f = (const float*)d_in[3];
    const float* W1b = (const float*)d_in[4];
    const float* U1b = (const float*)d_in[5];
    const float* b1b = (const float*)d_in[6];
    const float* W2f = (const float*)d_in[7];
    const float* U2f = (const float*)d_in[8];
    const float* b2f = (const float*)d_in[9];
    const float* W2b = (const float*)d_in[10];
    const float* U2b = (const float*)d_in[11];
    const float* b2b = (const float*)d_in[12];
    const float* Wd  = (const float*)d_in[13];
    const float* bd  = (const float*)d_in[14];

    // Workspace layout (160 MiB):
    //   xz : 65536 x 512 f32 = 128 MiB   (reused by layer 1 and layer 2)
    //   h  : 65536 x 128 f32 =  32 MiB   (h1, then overwritten by h2)
    float* xz = (float*)d_ws;
    float* h  = (float*)((char*)d_ws + (size_t)65536 * 512 * 4);

    const dim3 gemm_grid(4, 512);      // n-tile FASTEST (A-tile L2 sharing)
    const dim3 rec_grid(256);          // 128 batch x 2 directions
    const dim3 dense_grid(1024);       // 65536/64 rows

    // Layer 1
    gemm_xz_mfma2<<<gemm_grid, dim3(256), 0, stream>>>(x, W1f, W1b, b1f, b1b, xz);
    lstm_rec_qp<<<rec_grid, dim3(512), 0, stream>>>(xz, U1f, U1b, h);
    // Layer 2
    gemm_xz_mfma2<<<gemm_grid, dim3(256), 0, stream>>>(h, W2f, W2b, b2f, b2b, xz);
    lstm_rec_qp<<<rec_grid, dim3(512), 0, stream>>>(xz, U2f, U2b, h);
    // Head
    dense_softmax<<<dense_grid, dim3(256), 0, stream>>>(h, Wd, bd, (float*)d_out);
}